// Round 6
// baseline (245.538 us; speedup 1.0000x reference)
//
#include <hip/hip_runtime.h>
#include <cstdint>

#define BB 8
#define CC 128
#define HH 96
#define WW 160
#define HWsz (HH * WW)          // 15360
#define TH 8
#define TW 32
#define NWAVES 3                // 3 dy values per block, one per wave
#define NTHREADS (NWAVES * 64)  // 192
#define NTILES (BB * (HH / TH) * (WW / TW))   // 480 spatial tiles
#define NBLOCKS (3 * NTILES)                  // 1440: x3 dy-groups

// No LDS, no barriers: waves are fully independent. Occupancy is bounded only
// by VGPR (<=128 -> 4 waves/SIMD = 16 waves/CU). R1-R5 evidence: the 9-wave
// barrier-coupled block never got >1 block/CU resident -> 75% idle pipes.
extern "C" __global__ void __launch_bounds__(NTHREADS, 4)
corr81_kernel(const float* __restrict__ x1, const float* __restrict__ x2,
              float* __restrict__ out)
{
  const int tid  = threadIdx.x;
  const int wv   = tid >> 6;     // 0..2 (dy within group)
  const int lane = tid & 63;
  const int r    = lane >> 3;    // tile row 0..7
  const int j    = lane & 7;     // w-slot 0..7 (4 px each)

  const int bid = blockIdx.x;
  const int wt  = bid % (WW / TW);                 // 0..4
  const int ht  = (bid / (WW / TW)) % (HH / TH);   // 0..11
  const int b   = (bid / ((WW / TW) * (HH / TH))) % BB;
  const int g   = bid / NTILES;                    // dy-group 0..2
  const int h0  = ht * TH;
  const int w0  = wt * TW;

  const int dyi = 3 * g + wv;          // 0..8
  const int dy  = dyi - 4;             // -4..4
  const int orow = h0 + r;             // output row
  int srow = orow + dy;                // x2 source row, replicate-clamped
  srow = srow < 0 ? 0 : (srow > HH - 1 ? HH - 1 : srow);

  // x2 window words for this thread's 4 pixels: [c1-4, c1+8), c1 = w0+4j.
  // Three aligned float4 segments; only seg0 can underflow (left edge) and
  // only seg2 can overflow (right edge) -> clamp starts, fix up in registers.
  const int c1 = w0 + 4 * j;
  int s0 = c1 - 4; s0 = s0 < 0 ? 0 : s0;
  const int s1 = c1;
  int s2 = c1 + 4; s2 = s2 > WW - 4 ? WW - 4 : s2;

  const bool ledge = (w0 == 0);            // block-uniform guards
  const bool redge = (w0 == WW - TW);

  const float* x1p = x1 + (size_t)b * CC * HWsz + (size_t)orow * WW + c1;
  const float* x2p = x2 + (size_t)b * CC * HWsz + (size_t)srow * WW;

  float acc[9][4];
#pragma unroll
  for (int dx = 0; dx < 9; ++dx)
#pragma unroll
    for (int p = 0; p < 4; ++p) acc[dx][p] = 0.f;

#pragma unroll 2
  for (int c = 0; c < CC; ++c) {
    const size_t coff = (size_t)c * HWsz;
    const float4 a4 = *(const float4*)(x1p + coff);
    const float4 f0 = *(const float4*)(x2p + coff + s0);
    const float4 f1 = *(const float4*)(x2p + coff + s1);
    const float4 f2 = *(const float4*)(x2p + coff + s2);
    float w12[12] = {f0.x, f0.y, f0.z, f0.w,
                     f1.x, f1.y, f1.z, f1.w,
                     f2.x, f2.y, f2.z, f2.w};
    if (ledge) {                 // only wt==0 blocks pay this
      if (j == 0) { w12[0] = w12[4]; w12[1] = w12[4]; w12[2] = w12[4]; w12[3] = w12[4]; }
    }
    if (redge) {                 // only wt==4 blocks pay this
      if (j == 7) { w12[8] = w12[7]; w12[9] = w12[7]; w12[10] = w12[7]; w12[11] = w12[7]; }
    }
    const float av[4] = {a4.x, a4.y, a4.z, a4.w};
#pragma unroll
    for (int dx = 0; dx < 9; ++dx)
#pragma unroll
      for (int p = 0; p < 4; ++p)
        acc[dx][p] = fmaf(av[p], w12[dx + p], acc[dx][p]);
  }

  // out[((b*81 + dyi*9+dx)*H + orow)*W + c1 ...], scale 1/8
  float* op = out + (((size_t)b * 81 + (size_t)dyi * 9) * HH + orow) * WW + c1;
#pragma unroll
  for (int dx = 0; dx < 9; ++dx) {
    float4 v;
    v.x = acc[dx][0] * 0.125f;
    v.y = acc[dx][1] * 0.125f;
    v.z = acc[dx][2] * 0.125f;
    v.w = acc[dx][3] * 0.125f;
    *(float4*)(op + (size_t)dx * HWsz) = v;
  }
}

extern "C" void kernel_launch(void* const* d_in, const int* in_sizes, int n_in,
                              void* d_out, int out_size, void* d_ws, size_t ws_size,
                              hipStream_t stream) {
  const float* x1 = (const float*)d_in[0];
  const float* x2 = (const float*)d_in[1];
  float* out = (float*)d_out;
  corr81_kernel<<<dim3(NBLOCKS), dim3(NTHREADS), 0, stream>>>(x1, x2, out);
}